// Round 1
// baseline (192.315 us; speedup 1.0000x reference)
//
#include <hip/hip_runtime.h>
#include <math.h>

#define Bn 8
#define Cn 80
#define Hn 128
#define Wn 128
#define On 128

// ---------------------------------------------------------------------------
// Block-level reduction of 3 doubles (256 threads) + atomic accumulate to ws
// ---------------------------------------------------------------------------
__device__ __forceinline__ void block_reduce3(double v0, double v1, double v2,
                                              double* ws) {
    __shared__ double sm[3 * 256];
    int t = threadIdx.x;
    sm[t]       = v0;
    sm[256 + t] = v1;
    sm[512 + t] = v2;
    __syncthreads();
    for (int s = 128; s > 0; s >>= 1) {
        if (t < s) {
            sm[t]       += sm[t + s];
            sm[256 + t] += sm[256 + t + s];
            sm[512 + t] += sm[512 + t + s];
        }
        __syncthreads();
    }
    if (t == 0) {
        atomicAdd(&ws[0], sm[0]);
        atomicAdd(&ws[1], sm[256]);
        atomicAdd(&ws[2], sm[512]);
    }
}

// ---------------------------------------------------------------------------
// Focal loss: grid-stride over B*C*H*W elements, float4 vectorized.
// Accumulates pos_loss (ws[0]), neg_loss (ws[1]), num_pos (ws[2]).
// ---------------------------------------------------------------------------
__global__ __launch_bounds__(256) void focal_kernel(
    const float4* __restrict__ hm_out, const float4* __restrict__ hm_gt,
    const float4* __restrict__ hm_mask, double* __restrict__ ws) {
    const int n4 = Bn * Cn * Hn * Wn / 4;
    double pl = 0.0, nl = 0.0, npos = 0.0;
    for (int i = blockIdx.x * blockDim.x + threadIdx.x; i < n4;
         i += gridDim.x * blockDim.x) {
        float4 xo = hm_out[i];
        float4 xg = hm_gt[i];
        float4 xm = hm_mask[i];
        const float* po = (const float*)&xo;
        const float* pg = (const float*)&xg;
        const float* pm = (const float*)&xm;
#pragma unroll
        for (int k = 0; k < 4; ++k) {
            float x = po[k];
            float g = pg[k] * pm[k];
            float s = 1.0f / (1.0f + expf(-x));
            float pred = fminf(fmaxf(s, 1e-6f), 1.0f - 1e-6f);
            if (g == 1.0f) {
                float om = 1.0f - pred;
                pl += (double)(logf(pred) * om * om);
                npos += 1.0;
            } else if (g < 1.0f) {
                float om = 1.0f - g;
                float w = om * om;
                w *= w;  // (1-g)^4
                nl += (double)(logf(1.0f - pred) * pred * pred * w);
            }
        }
    }
    block_reduce3(pl, nl, npos, ws);
}

// ---------------------------------------------------------------------------
// KL kernel: one block per (b,c) pair, one thread per object (O=128).
// Gaussian LS fit in log domain over the 5x5 patch; closed-form pinv:
//   bx = sum(x*lz)/50, by = sum(y*lz)/50,
//   ax = sum((x^2-2)*lz)/70, ay = sum((y^2-2)*lz)/70
// Accumulates kl_sum into ws[3].
// ---------------------------------------------------------------------------
__global__ __launch_bounds__(On) void kl_kernel(
    const float* __restrict__ hm_out, const int* __restrict__ ct_ind,
    const float* __restrict__ sigma_wh, const int* __restrict__ sigmawh_mask,
    double* __restrict__ ws) {
    int bc = blockIdx.x;   // b*Cn + c
    int o = threadIdx.x;   // object index

    int m = sigmawh_mask[bc * On + o];

    // cnt = sum of mask over this (b,c)
    __shared__ int smi[On];
    smi[o] = m;
    __syncthreads();
    for (int s = On / 2; s > 0; s >>= 1) {
        if (o < s) smi[o] += smi[o + s];
        __syncthreads();
    }
    int cnt = smi[0];

    double kl = 0.0;
    if (m == 1 && o < cnt) {
        int xi = ct_ind[(bc * On + o) * 2 + 0];
        int yi = ct_ind[(bc * On + o) * 2 + 1];
        xi = min(max(xi, 2), Wn - 3);
        yi = min(max(yi, 2), Hn - 3);

        const float* base = hm_out + ((size_t)bc * Hn + yi) * Wn + xi;

        double Sbx = 0.0, Sby = 0.0, Sax = 0.0, Say = 0.0;
#pragma unroll
        for (int py = 0; py < 5; ++py) {
#pragma unroll
            for (int px = 0; px < 5; ++px) {
                float v = base[(py - 2) * Wn + (px - 2)];
                float sg = 1.0f / (1.0f + expf(-v));
                double lz = (double)logf(sg);
                int fx = px - 2, fy = py - 2;
                Sbx += (double)fx * lz;
                Sby += (double)fy * lz;
                Sax += (double)(fx * fx - 2) * lz;
                Say += (double)(fy * fy - 2) * lz;
            }
        }
        float bx = (float)(Sbx * (1.0 / 50.0));
        float by = (float)(Sby * (1.0 / 50.0));
        float ax = (float)(Sax * (1.0 / 70.0));
        float ay = (float)(Say * (1.0 / 70.0));

        float ax_s = (fabsf(ax) < 1e-12f) ? -1.0f : ax;
        float ay_s = (fabsf(ay) < 1e-12f) ? -1.0f : ay;
        float sw2 = -0.5f / ax_s;
        float sh2 = -0.5f / ay_s;

        if (sw2 > 0.0f && sh2 > 0.0f) {
            float mw = -bx / (2.0f * ax_s);
            float mh = -by / (2.0f * ay_s);
            float sgw = sigma_wh[(bc * On + o) * 2 + 0];
            float sgh = sigma_wh[(bc * On + o) * 2 + 1];
            float sgw2 = sgw * sgw;
            float sgh2 = sgh * sgh;
            float klv = 0.5f * logf(sgw2 * sgh2 / (sw2 * sh2)) - 1.0f +
                        0.5f * (sw2 / sgw2 + sh2 / sgh2) +
                        0.5f * (mw * mw / sgw2 + mh * mh / sgh2);
            kl = (double)klv;
        }
    }

    // block reduce kl
    __shared__ double smd[On];
    smd[o] = kl;
    __syncthreads();
    for (int s = On / 2; s > 0; s >>= 1) {
        if (o < s) smd[o] += smd[o + s];
        __syncthreads();
    }
    if (o == 0) atomicAdd(&ws[3], smd[0]);
}

// ---------------------------------------------------------------------------
// Finalize: d_out[0] = kl_sum, d_out[1] = focal
// ---------------------------------------------------------------------------
__global__ void finalize_kernel(const double* __restrict__ ws,
                                float* __restrict__ out) {
    double pl = ws[0], nl = ws[1], npos = ws[2], kl = ws[3];
    double focal = (npos == 0.0) ? (-nl) : (-(pl + nl) / npos);
    out[0] = (float)kl;
    out[1] = (float)focal;
}

extern "C" void kernel_launch(void* const* d_in, const int* in_sizes, int n_in,
                              void* d_out, int out_size, void* d_ws,
                              size_t ws_size, hipStream_t stream) {
    const float* hm_out       = (const float*)d_in[0];
    const float* hm_gt        = (const float*)d_in[1];
    const int*   ct_ind       = (const int*)d_in[2];
    const float* sigma_wh     = (const float*)d_in[3];
    const float* hm_mask      = (const float*)d_in[4];
    const int*   sigmawh_mask = (const int*)d_in[5];
    double* ws = (double*)d_ws;
    float* out = (float*)d_out;

    hipMemsetAsync(ws, 0, 4 * sizeof(double), stream);

    focal_kernel<<<1024, 256, 0, stream>>>(
        (const float4*)hm_out, (const float4*)hm_gt, (const float4*)hm_mask, ws);

    kl_kernel<<<Bn * Cn, On, 0, stream>>>(hm_out, ct_ind, sigma_wh,
                                          sigmawh_mask, ws);

    finalize_kernel<<<1, 1, 0, stream>>>(ws, out);
}

// Round 2
// 164.767 us; speedup vs baseline: 1.1672x; 1.1672x over previous
//
#include <hip/hip_runtime.h>
#include <math.h>

#define Bn 8
#define Cn 80
#define Hn 128
#define Wn 128
#define On 128

// Focal grid: exact cover, 4 float4 per thread.
#define FOCAL_BLOCKS 2560
#define FOCAL_THREADS 256
#define FOCAL_ITERS 4
// n4 = B*C*H*W/4 = 2,621,440 = 2560*256*4 exactly.

// ws layout (doubles):
//   [0          .. 2559]  focal pos_loss partials (per block)
//   [2560       .. 5119]  focal neg_loss partials
//   [5120       .. 7679]  focal num_pos partials
//   [7680       .. 8319]  kl partials (640 blocks)
#define WS_PL 0
#define WS_NL 2560
#define WS_NP 5120
#define WS_KL 7680
#define KL_BLOCKS (Bn * Cn)

#define LOG_EPS -13.815511f        // log(1e-6)
#define LOG_1MEPS -1.0000005e-6f   // log(1 - 1e-6)

// ---------------------------------------------------------------------------
// Focal loss: branch-free fp32 math, per-block partial written to ws.
// log(sigmoid(x)) = -log(1+exp(-x)); log(1-sigmoid(x)) = -x + log(sigmoid(x))
// Clamp of pred to [1e-6, 1-1e-6] == clamp of the logs (log is monotone).
// ---------------------------------------------------------------------------
__global__ __launch_bounds__(FOCAL_THREADS) void focal_kernel(
    const float4* __restrict__ hm_out, const float4* __restrict__ hm_gt,
    const float4* __restrict__ hm_mask, double* __restrict__ ws) {
    const int base = blockIdx.x * (FOCAL_THREADS * FOCAL_ITERS) + threadIdx.x;

    // Load everything first (12 independent dwordx4 loads).
    float4 xo[FOCAL_ITERS], xg[FOCAL_ITERS], xm[FOCAL_ITERS];
#pragma unroll
    for (int it = 0; it < FOCAL_ITERS; ++it) {
        int i = base + it * FOCAL_THREADS;
        xo[it] = hm_out[i];
        xg[it] = hm_gt[i];
        xm[it] = hm_mask[i];
    }

    float pl = 0.0f, nl = 0.0f, npos = 0.0f;
#pragma unroll
    for (int it = 0; it < FOCAL_ITERS; ++it) {
        const float* po = (const float*)&xo[it];
        const float* pg = (const float*)&xg[it];
        const float* pm = (const float*)&xm[it];
#pragma unroll
        for (int k = 0; k < 4; ++k) {
            float x = po[k];
            float g = pg[k] * pm[k];
            float e = expf(-x);                   // e^-x
            float s = 1.0f / (1.0f + e);          // sigmoid
            float ls = -logf(1.0f + e);           // log(sigmoid)
            float l1s = ls - x;                   // log(1-sigmoid)
            // clamped logs (pred clip 1e-6..1-1e-6)
            float ls_c = fminf(fmaxf(ls, LOG_EPS), LOG_1MEPS);
            float l1s_c = fminf(fmaxf(l1s, LOG_EPS), LOG_1MEPS);
            float pred = fminf(fmaxf(s, 1e-6f), 1.0f - 1e-6f);

            float om = 1.0f - pred;
            float pos_c = ls_c * om * om;
            float omg = 1.0f - g;
            float w4 = omg * omg;
            w4 *= w4;
            float neg_c = l1s_c * pred * pred * w4;

            bool is_pos = (g == 1.0f);
            bool is_neg = (g < 1.0f);
            pl += is_pos ? pos_c : 0.0f;
            npos += is_pos ? 1.0f : 0.0f;
            nl += is_neg ? neg_c : 0.0f;
        }
    }

    // wave reduce (64 lanes) in float, then cross-wave in double via LDS.
    for (int off = 32; off > 0; off >>= 1) {
        pl += __shfl_down(pl, off, 64);
        nl += __shfl_down(nl, off, 64);
        npos += __shfl_down(npos, off, 64);
    }
    __shared__ double sm[3 * (FOCAL_THREADS / 64)];
    int wave = threadIdx.x >> 6;
    int lane = threadIdx.x & 63;
    if (lane == 0) {
        sm[wave * 3 + 0] = (double)pl;
        sm[wave * 3 + 1] = (double)nl;
        sm[wave * 3 + 2] = (double)npos;
    }
    __syncthreads();
    if (threadIdx.x == 0) {
        double a = 0, b = 0, c = 0;
#pragma unroll
        for (int w = 0; w < FOCAL_THREADS / 64; ++w) {
            a += sm[w * 3 + 0];
            b += sm[w * 3 + 1];
            c += sm[w * 3 + 2];
        }
        ws[WS_PL + blockIdx.x] = a;
        ws[WS_NL + blockIdx.x] = b;
        ws[WS_NP + blockIdx.x] = c;
    }
}

// ---------------------------------------------------------------------------
// KL kernel: one block per (b,c), one thread per object. fp32 throughout.
// Closed-form pinv of the 5x5 log-Gaussian LS fit:
//   bx = sum(x*lz)/50, by = sum(y*lz)/50,
//   ax = sum((x^2-2)*lz)/70, ay = sum((y^2-2)*lz)/70
// ---------------------------------------------------------------------------
__global__ __launch_bounds__(On) void kl_kernel(
    const float* __restrict__ hm_out, const int* __restrict__ ct_ind,
    const float* __restrict__ sigma_wh, const int* __restrict__ sigmawh_mask,
    double* __restrict__ ws) {
    int bc = blockIdx.x;
    int o = threadIdx.x;

    int m = sigmawh_mask[bc * On + o];

    __shared__ int smi[On];
    smi[o] = m;
    __syncthreads();
    for (int s = On / 2; s > 0; s >>= 1) {
        if (o < s) smi[o] += smi[o + s];
        __syncthreads();
    }
    int cnt = smi[0];

    float kl = 0.0f;
    if (m == 1 && o < cnt) {
        int xi = ct_ind[(bc * On + o) * 2 + 0];
        int yi = ct_ind[(bc * On + o) * 2 + 1];
        xi = min(max(xi, 2), Wn - 3);
        yi = min(max(yi, 2), Hn - 3);

        const float* base = hm_out + ((size_t)bc * Hn + yi) * Wn + xi;

        float v[25];
#pragma unroll
        for (int py = 0; py < 5; ++py)
#pragma unroll
            for (int px = 0; px < 5; ++px)
                v[py * 5 + px] = base[(py - 2) * Wn + (px - 2)];

        float Sbx = 0.f, Sby = 0.f, Sax = 0.f, Say = 0.f;
#pragma unroll
        for (int py = 0; py < 5; ++py) {
#pragma unroll
            for (int px = 0; px < 5; ++px) {
                float x = v[py * 5 + px];
                float lz = -logf(1.0f + expf(-x));  // log(sigmoid), unclamped
                float fx = (float)(px - 2), fy = (float)(py - 2);
                Sbx += fx * lz;
                Sby += fy * lz;
                Sax += (fx * fx - 2.0f) * lz;
                Say += (fy * fy - 2.0f) * lz;
            }
        }
        float bx = Sbx * (1.0f / 50.0f);
        float by = Sby * (1.0f / 50.0f);
        float ax = Sax * (1.0f / 70.0f);
        float ay = Say * (1.0f / 70.0f);

        float ax_s = (fabsf(ax) < 1e-12f) ? -1.0f : ax;
        float ay_s = (fabsf(ay) < 1e-12f) ? -1.0f : ay;
        float sw2 = -0.5f / ax_s;
        float sh2 = -0.5f / ay_s;

        if (sw2 > 0.0f && sh2 > 0.0f) {
            float mw = -bx / (2.0f * ax_s);
            float mh = -by / (2.0f * ay_s);
            float sgw = sigma_wh[(bc * On + o) * 2 + 0];
            float sgh = sigma_wh[(bc * On + o) * 2 + 1];
            float sgw2 = sgw * sgw;
            float sgh2 = sgh * sgh;
            kl = 0.5f * logf(sgw2 * sgh2 / (sw2 * sh2)) - 1.0f +
                 0.5f * (sw2 / sgw2 + sh2 / sgh2) +
                 0.5f * (mw * mw / sgw2 + mh * mh / sgh2);
        }
    }

    // wave reduce then cross-wave (2 waves)
    for (int off = 32; off > 0; off >>= 1) kl += __shfl_down(kl, off, 64);
    __shared__ double smd[On / 64];
    int wave = o >> 6;
    int lane = o & 63;
    if (lane == 0) smd[wave] = (double)kl;
    __syncthreads();
    if (o == 0) ws[WS_KL + bc] = smd[0] + smd[1];
}

// ---------------------------------------------------------------------------
// Finalize: reduce all partials, write d_out[0]=kl_sum, d_out[1]=focal.
// ---------------------------------------------------------------------------
__global__ __launch_bounds__(256) void finalize_kernel(
    const double* __restrict__ ws, float* __restrict__ out) {
    int t = threadIdx.x;
    double pl = 0, nl = 0, np = 0, kl = 0;
    for (int i = t; i < FOCAL_BLOCKS; i += 256) {
        pl += ws[WS_PL + i];
        nl += ws[WS_NL + i];
        np += ws[WS_NP + i];
    }
    for (int i = t; i < KL_BLOCKS; i += 256) kl += ws[WS_KL + i];

    __shared__ double sm[4 * 256];
    sm[t] = pl;
    sm[256 + t] = nl;
    sm[512 + t] = np;
    sm[768 + t] = kl;
    __syncthreads();
    for (int s = 128; s > 0; s >>= 1) {
        if (t < s) {
            sm[t] += sm[t + s];
            sm[256 + t] += sm[256 + t + s];
            sm[512 + t] += sm[512 + t + s];
            sm[768 + t] += sm[768 + t + s];
        }
        __syncthreads();
    }
    if (t == 0) {
        double focal = (sm[512] == 0.0) ? (-sm[256]) : (-(sm[0] + sm[256]) / sm[512]);
        out[0] = (float)sm[768];
        out[1] = (float)focal;
    }
}

extern "C" void kernel_launch(void* const* d_in, const int* in_sizes, int n_in,
                              void* d_out, int out_size, void* d_ws,
                              size_t ws_size, hipStream_t stream) {
    const float* hm_out       = (const float*)d_in[0];
    const float* hm_gt        = (const float*)d_in[1];
    const int*   ct_ind       = (const int*)d_in[2];
    const float* sigma_wh     = (const float*)d_in[3];
    const float* hm_mask      = (const float*)d_in[4];
    const int*   sigmawh_mask = (const int*)d_in[5];
    double* ws = (double*)d_ws;
    float* out = (float*)d_out;

    focal_kernel<<<FOCAL_BLOCKS, FOCAL_THREADS, 0, stream>>>(
        (const float4*)hm_out, (const float4*)hm_gt, (const float4*)hm_mask, ws);

    kl_kernel<<<KL_BLOCKS, On, 0, stream>>>(hm_out, ct_ind, sigma_wh,
                                            sigmawh_mask, ws);

    finalize_kernel<<<1, 256, 0, stream>>>(ws, out);
}